// Round 5
// baseline (177.980 us; speedup 1.0000x reference)
//
#include <hip/hip_runtime.h>

// Problem constants: B=2, S=2048, D=1024, H=16, HD=64
#define BB 2
#define SS 2048
#define DD 1024
#define HH 16
#define HD 64
#define MM (BB*SS)   // 4096 rows

typedef __bf16 bf16x8 __attribute__((ext_vector_type(8)));
typedef short  s16x4  __attribute__((ext_vector_type(4)));
typedef float  f32x4  __attribute__((ext_vector_type(4)));

#ifndef __has_builtin
#define __has_builtin(x) 0
#endif

__device__ __forceinline__ unsigned short f2bf(float f) {
    unsigned int u = __float_as_uint(f);
    u = (u + 0x7fffu + ((u >> 16) & 1u)) >> 16;  // RNE
    return (unsigned short)u;
}
__device__ __forceinline__ unsigned int pack2(float a, float b) {
    return (unsigned int)f2bf(a) | ((unsigned int)f2bf(b) << 16);
}
// fast pack (round-half-up): 2 adds + 1 v_perm
__device__ __forceinline__ unsigned int pack2_fast(float a, float b) {
#if __has_builtin(__builtin_amdgcn_perm)
    return __builtin_amdgcn_perm(__float_as_uint(b) + 0x8000u,
                                 __float_as_uint(a) + 0x8000u, 0x07060302u);
#else
    return ((__float_as_uint(a) + 0x8000u) >> 16) |
           ((__float_as_uint(b) + 0x8000u) & 0xffff0000u);
#endif
}

// async global->LDS, 16B per lane; LDS dest = wave-uniform base + lane*16
__device__ __forceinline__ void gload_lds16(const unsigned short* g, unsigned short* l) {
    __builtin_amdgcn_global_load_lds(
        (const __attribute__((address_space(1))) void*)g,
        (__attribute__((address_space(3))) void*)l, 16, 0, 0);
}

// ---------------- fused prep: cast x -> bf16, transpose W -> bf16 [n][k] ----------------
// blocks [0,2048): cast_x (8 elems/thread).  blocks [2048,6144): W transpose.
__global__ __launch_bounds__(256) void prep_kernel(const float* __restrict__ x,
                                                   const float* __restrict__ Wq,
                                                   const float* __restrict__ Wk,
                                                   const float* __restrict__ Wv,
                                                   const float* __restrict__ Wo,
                                                   unsigned short* __restrict__ Xb,
                                                   unsigned short* __restrict__ Wqkvt,
                                                   unsigned short* __restrict__ Wot) {
    __shared__ float tile[32][33];
    const int bx = blockIdx.x;
    const int t = threadIdx.x;
    if (bx < 2048) {
        int gid = bx * 256 + t;
        int i = gid * 8;
        float4 a = *(const float4*)(x + i);
        float4 b = *(const float4*)(x + i + 4);
        uint4 o;
        o.x = pack2(a.x, a.y); o.y = pack2(a.z, a.w);
        o.z = pack2(b.x, b.y); o.w = pack2(b.z, b.w);
        ((uint4*)Xb)[gid] = o;
        return;
    }
    int pb = bx - 2048;
    int p = pb >> 10, rem = pb & 1023;
    int bxx = rem & 31, byy = rem >> 5;
    const float* src = (p == 0) ? Wq : (p == 1) ? Wk : (p == 2) ? Wv : Wo;
    unsigned short* dst = (p == 3) ? Wot : (Wqkvt + (size_t)p * DD * DD);
    int tx = t & 31, ty = t >> 5;
    int n = bxx * 32 + tx;
#pragma unroll
    for (int i = 0; i < 4; ++i) {
        int k = byy * 32 + ty + i * 8;
        tile[ty + i * 8][tx] = src[k * DD + n];
    }
    __syncthreads();
#pragma unroll
    for (int i = 0; i < 4; ++i) {
        int n2 = bxx * 32 + ty + i * 8;
        int k2 = byy * 32 + tx;
        dst[n2 * DD + k2] = f2bf(tile[tx][ty + i * 8]);
    }
}

// ============ 128x128-tile GEMM K-loop, global_load_lds staging, xor-swizzled ============
// Phys granule p (16B) of LDS row r holds logical granule p^(r&7): DMA writes stay
// contiguous (conflict-free), fragment b128 reads spread over all 8 granule groups
// (1 lane/group/phase = structural minimum, zero conflicts). Rows are 128B = full
// bank line — do NOT shorten rows (64B rows -> 4-way conflicts, r3 lesson).
#define GEMM_K_LOOP(Aglob, Bglob)                                                 \
    __shared__ unsigned short smem[128 * 132];                                    \
    unsigned short (*As)[64]  = (unsigned short(*)[64])smem;                      \
    unsigned short (*Bs)[64]  = (unsigned short(*)[64])(smem + 128 * 64);         \
    unsigned short (*Es)[132] = (unsigned short(*)[132])smem;                     \
    const int n0 = blockIdx.x * 128, m0 = blockIdx.y * 128;                       \
    const int t = threadIdx.x;                                                    \
    const int wave = t >> 6, lane = t & 63;                                       \
    const int wm = wave >> 1, wn = wave & 1;                                      \
    const int l15 = lane & 15, quad = lane >> 4;                                  \
    const int lr = lane >> 3, lg = (lane & 7);                                    \
    const int lc = (lg ^ lr) * 8;   /* swizzled source granule */                 \
    f32x4 acc[4][4];                                                              \
    _Pragma("unroll") for (int i = 0; i < 4; ++i)                                 \
        _Pragma("unroll") for (int j = 0; j < 4; ++j) acc[i][j] = f32x4{0,0,0,0}; \
    for (int kt = 0; kt < 16; ++kt) {                                             \
        if (kt) __syncthreads();                                                  \
        _Pragma("unroll") for (int i = 0; i < 4; ++i) {                           \
            int row = wave * 32 + i * 8;                                          \
            gload_lds16(Aglob + (size_t)(m0 + row + lr) * DD + kt * 64 + lc, &As[row][0]); \
            gload_lds16(Bglob + (size_t)(n0 + row + lr) * DD + kt * 64 + lc, &Bs[row][0]); \
        }                                                                         \
        __syncthreads();                                                          \
        _Pragma("unroll") for (int kh = 0; kh < 2; ++kh) {                        \
            bf16x8 af[4], bfr[4];                                                 \
            _Pragma("unroll") for (int s = 0; s < 4; ++s)                         \
                af[s] = *(const bf16x8*)&As[wm * 64 + s * 16 + l15][((kh * 4 + quad) ^ (l15 & 7)) * 8]; \
            _Pragma("unroll") for (int s = 0; s < 4; ++s)                         \
                bfr[s] = *(const bf16x8*)&Bs[wn * 64 + s * 16 + l15][((kh * 4 + quad) ^ (l15 & 7)) * 8]; \
            _Pragma("unroll") for (int i = 0; i < 4; ++i)                         \
                _Pragma("unroll") for (int j = 0; j < 4; ++j)                     \
                    acc[i][j] = __builtin_amdgcn_mfma_f32_16x16x32_bf16(af[i], bfr[j], acc[i][j], 0, 0, 0); \
        }                                                                         \
    }                                                                             \
    __syncthreads();   /* K-loop done; smem reusable */

// ---------------- QKV fused GEMM; LDS-transpose epilogue; Q pre-scaled ----------------
// (round-0 structure: measured ~28 us = ~920 TF, at the 2-barrier-structure ceiling)
__global__ __launch_bounds__(256) void qkv_gemm_kernel(const unsigned short* __restrict__ Xb,
                                                       const unsigned short* __restrict__ Wt,
                                                       unsigned short* __restrict__ Qg,
                                                       unsigned short* __restrict__ Kg,
                                                       unsigned short* __restrict__ Vt) {
    GEMM_K_LOOP(Xb, Wt)
    const int p = n0 >> 10;   // projection uniform per block
    const float qs = (p == 0) ? 0.18033688011112042f : 1.0f;  // log2(e)/sqrt(HD) folded into Q
    if (p < 2) {
#pragma unroll
        for (int sm = 0; sm < 4; ++sm)
#pragma unroll
            for (int sn = 0; sn < 4; ++sn)
#pragma unroll
                for (int i = 0; i < 4; ++i)
                    Es[wm * 64 + sm * 16 + quad * 4 + i][wn * 64 + sn * 16 + l15] = f2bf(acc[sm][sn][i] * qs);
    } else {
#pragma unroll
        for (int sm = 0; sm < 4; ++sm)
#pragma unroll
            for (int sn = 0; sn < 4; ++sn)
#pragma unroll
                for (int i = 0; i < 4; ++i)
                    Es[wn * 64 + sn * 16 + l15][wm * 64 + sm * 16 + quad * 4 + i] = f2bf(acc[sm][sn][i]);
    }
    __syncthreads();
    const int h0 = (n0 & 1023) >> 6;
    if (p < 2) {
        unsigned short* dst0 = p ? Kg : Qg;
        int ml = t >> 1, seg = t & 1;
        int gm = m0 + ml, b = gm >> 11, s = gm & 2047;
        unsigned short* dptr = dst0 + ((size_t)(b * HH + h0 + seg) * SS + s) * HD;
#pragma unroll
        for (int j = 0; j < 8; ++j)
            *(uint4*)(dptr + j * 8) = *(const uint4*)&Es[ml][seg * 64 + j * 8];
    } else {
        int nl = t >> 1, mh = t & 1;
        int h = h0 + (nl >> 6), hd = nl & 63;
        int b = m0 >> 11, s0 = (m0 & 2047) + mh * 64;
        unsigned short* dptr = Vt + ((size_t)(b * HH + h) * HD + hd) * SS + s0;
#pragma unroll
        for (int j = 0; j < 8; ++j)
            *(uint4*)(dptr + j * 8) = *(const uint4*)&Es[nl][mh * 64 + j * 8];
    }
}

// ---------------- Output projection: out = Ctx @ Wo + bo (fp32 out) ----------------
__global__ __launch_bounds__(256) void out_gemm_kernel(const unsigned short* __restrict__ Ctxb,
                                                       const unsigned short* __restrict__ Wot,
                                                       const float* __restrict__ bo,
                                                       float* __restrict__ out) {
    GEMM_K_LOOP(Ctxb, Wot)
    (void)Es;
#pragma unroll
    for (int sn = 0; sn < 4; ++sn) {
        int gn = n0 + wn * 64 + sn * 16 + l15;
        float bias = bo[gn];
#pragma unroll
        for (int sm = 0; sm < 4; ++sm)
#pragma unroll
            for (int i = 0; i < 4; ++i) {
                int gm = m0 + wm * 64 + sm * 16 + quad * 4 + i;
                out[(size_t)gm * DD + gn] = acc[sm][sn][i] + bias;
            }
    }
}

// ---------------- MFMA flash attention (round-0 structure, proven fastest) ----------------
// 64-q blocks x 128-key double-buffered tiles, grid 1024 (2 dispatch rounds, big-first
// = dynamic load balance). NO setprio: on this barrier-lockstep 4-wave structure it
// measured -6 us (r4 A/B vs r0; matches m190's GEMM null/negative — setprio only pays
// on phase-split or 1-wave-per-block schedules). Riders kept: per-wave diagonal kbmax
// (work-only reduction behind equalizing barrier); skip final-tile barrier (no LDS
// writer follows -> one less full waitcnt drain per block).
__global__ __launch_bounds__(256) void attn_kernel(const unsigned short* __restrict__ Qg,
                                                   const unsigned short* __restrict__ Kg,
                                                   const unsigned short* __restrict__ Vt,
                                                   unsigned short* __restrict__ Ctxb) {
    __shared__ unsigned short Ks[2][128][64];
    __shared__ unsigned short Vs[2][64][128];

    const int bh = blockIdx.x;
    const int qt = (int)gridDim.y - 1 - (int)blockIdx.y;   // big tiles first
    const int t = threadIdx.x;
    const int wave = t >> 6, lane = t & 63;
    const int l15 = lane & 15, quad = lane >> 4;
    const int q0 = qt * 64;
    const int qmax = q0 + 63;
    const int b = bh >> 4, h = bh & 15;

    const unsigned short* Qb = Qg + (size_t)bh * SS * HD;
    const unsigned short* Kb = Kg + (size_t)bh * SS * HD;
    const unsigned short* Vb = Vt + (size_t)bh * HD * SS;

    // Q fragment (B operand): B[n=q=l15][k=hd=hh*32+quad*8+j]; Q pre-scaled
    const int qrow = q0 + wave * 16 + l15;
    bf16x8 bq[2];
#pragma unroll
    for (int hh = 0; hh < 2; ++hh)
        bq[hh] = *(const bf16x8*)(Qb + (size_t)qrow * HD + hh * 32 + quad * 8);

    // DMA lane decomposition + swizzled source addresses
    const int rloc = lane >> 3, pcl = lane & 7;   // K: 8 rows x 8 granules (16B)
    const int vrl = lane >> 4, vgc = lane & 15;   // V: 4 rows x 16 granules (16B)
    const unsigned short* ksrc[4];
    const unsigned short* vsrc[4];
#pragma unroll
    for (int j = 0; j < 4; ++j) {
        int krow = (wave * 4 + j) * 8 + rloc;
        ksrc[j] = Kb + (size_t)krow * HD + (pcl ^ rloc) * 8;
        int vrow = wave * 16 + j * 4 + vrl;
        vsrc[j] = Vb + (size_t)vrow * SS + (vgc ^ (vrow & 15)) * 8;
    }

    f32x4 acc[4] = {f32x4{0,0,0,0}, f32x4{0,0,0,0}, f32x4{0,0,0,0}, f32x4{0,0,0,0}};
    float l = 0.f;   // lane-local partial; cross-quad reduce once at end
    const int nkt = (qmax >> 7) + 1;

    // prologue: tile 0 -> buf 0
#pragma unroll
    for (int j = 0; j < 4; ++j) {
        gload_lds16(ksrc[j], &Ks[0][(wave * 4 + j) * 8][0]);
        gload_lds16(vsrc[j], &Vs[0][wave * 16 + j * 4][0]);
    }
    __syncthreads();

    for (int kt = 0; kt < nkt; ++kt) {
        const int buf = kt & 1;
        const int k0 = kt * 128;
        if (kt + 1 < nkt) {
            const int nb = buf ^ 1;
#pragma unroll
            for (int j = 0; j < 4; ++j) {
                gload_lds16(ksrc[j] + (size_t)(kt + 1) * 128 * HD, &Ks[nb][(wave * 4 + j) * 8][0]);
                gload_lds16(vsrc[j] + (kt + 1) * 128,              &Vs[nb][wave * 16 + j * 4][0]);
            }
        }

        auto tile_body = [&](int kbmax, bool tail) {
#pragma unroll
            for (int kb = 0; kb < 8; ++kb) {
                if (kb >= kbmax) continue;   // wave-uniform branch
                // QK: S^T = K.Q^T  D[m=key][n=q]
                f32x4 St = f32x4{0, 0, 0, 0};
#pragma unroll
                for (int hh = 0; hh < 2; ++hh) {
                    bf16x8 ak = *(const bf16x8*)&Ks[buf][kb * 16 + l15][((hh * 4 + quad) ^ (l15 & 7)) * 8];
                    St = __builtin_amdgcn_mfma_f32_16x16x32_bf16(ak, bq[hh], St, 0, 0, 0);
                }
                if (tail) {
#pragma unroll
                    for (int r = 0; r < 4; ++r)
                        if (k0 + kb * 16 + quad * 4 + r > qrow) St[r] = -1e30f;
                }
                float e0 = __builtin_amdgcn_exp2f(St[0]);
                float e1 = __builtin_amdgcn_exp2f(St[1]);
                float e2 = __builtin_amdgcn_exp2f(St[2]);
                float e3 = __builtin_amdgcn_exp2f(St[3]);
                l += (e0 + e1) + (e2 + e3);
                uint2 uu;
                uu.x = pack2_fast(e0, e1);
                uu.y = pack2_fast(e2, e3);
                s16x4 ap = *(s16x4*)&uu;
                // PV: ctx += P @ V   (V^T swizzled b64 reads)
#pragma unroll
                for (int db = 0; db < 4; ++db) {
                    const int pg = (2 * kb + (quad >> 1)) ^ l15;
                    s16x4 bv = *(const s16x4*)&Vs[buf][db * 16 + l15][pg * 8 + (quad & 1) * 4];
                    acc[db] = __builtin_amdgcn_mfma_f32_16x16x16bf16_1k(ap, bv, acc[db], 0, 0, 0);
                }
            }
        };
        if (kt == nkt - 1) tile_body(((q0 - k0) >> 4) + wave + 1, true);  // per-wave diagonal bound
        else               tile_body(8, false);

        if (kt + 1 < nkt) __syncthreads();   // last tile: no LDS writer follows
    }

    // epilogue: reduce l across quads, ctx/l -> bf16 [B*S][D]
    l += __shfl_xor(l, 16, 64);
    l += __shfl_xor(l, 32, 64);
    float linv = 1.0f / l;
#pragma unroll
    for (int r = 0; r < 4; ++r) {
        float ir = __shfl(linv, quad * 4 + r, 64);
        int gq = q0 + wave * 16 + quad * 4 + r;
        size_t base = ((size_t)(b * SS + gq)) * DD + h * HD;
#pragma unroll
        for (int db = 0; db < 4; ++db)
            Ctxb[base + db * 16 + l15] = f2bf(acc[db][r] * ir);
    }
}

// ---------------- launcher ----------------
// Workspace (<= 48 MiB):
//   [0,8M)    Xb     bf16 [4096][1024]
//   [8M,14M)  Wqkvt  bf16 [3][1024][1024]   (W^T [n][k])
//   [14M,16M) Wot    bf16 [1024][1024]      (W^T)
//   [16M,24M) Qg     bf16 [32][2048][64]    (pre-scaled by log2e/8)
//   [24M,32M) Kg     bf16 [32][2048][64]
//   [32M,40M) Vt     bf16 [32][64][2048]    (transposed)
//   [40M,48M) Ctxb   bf16 [4096][1024]
extern "C" void kernel_launch(void* const* d_in, const int* in_sizes, int n_in,
                              void* d_out, int out_size, void* d_ws, size_t ws_size,
                              hipStream_t stream) {
    const float* x  = (const float*)d_in[0];
    const float* Wq = (const float*)d_in[1];
    const float* Wk = (const float*)d_in[2];
    const float* Wv = (const float*)d_in[3];
    const float* Wo = (const float*)d_in[4];
    const float* bo = (const float*)d_in[5];
    float* out = (float*)d_out;

    char* w = (char*)d_ws;
    unsigned short* Xb    = (unsigned short*)(w);
    unsigned short* Wqkvt = (unsigned short*)(w + (size_t)(8 << 20));
    unsigned short* Wot   = (unsigned short*)(w + (size_t)(14 << 20));
    unsigned short* Qg    = (unsigned short*)(w + (size_t)(16 << 20));
    unsigned short* Kg    = (unsigned short*)(w + (size_t)(24 << 20));
    unsigned short* Vt    = (unsigned short*)(w + (size_t)(32 << 20));
    unsigned short* Ctxb  = (unsigned short*)(w + (size_t)(40 << 20));

    prep_kernel<<<6144, 256, 0, stream>>>(x, Wq, Wk, Wv, Wo, Xb, Wqkvt, Wot);
    qkv_gemm_kernel<<<dim3(3 * DD / 128, MM / 128), 256, 0, stream>>>(Xb, Wqkvt, Qg, Kg, Vt);
    attn_kernel<<<dim3(BB * HH, SS / 64), 256, 0, stream>>>(Qg, Kg, Vt, Ctxb);
    out_gemm_kernel<<<dim3(DD / 128, MM / 128), 256, 0, stream>>>(Ctxb, Wot, bo, out);
}

// Round 6
// 173.296 us; speedup vs baseline: 1.0270x; 1.0270x over previous
//
#include <hip/hip_runtime.h>

// Problem constants: B=2, S=2048, D=1024, H=16, HD=64
#define BB 2
#define SS 2048
#define DD 1024
#define HH 16
#define HD 64
#define MM (BB*SS)   // 4096 rows

typedef __bf16 bf16x8 __attribute__((ext_vector_type(8)));
typedef short  s16x4  __attribute__((ext_vector_type(4)));
typedef float  f32x4  __attribute__((ext_vector_type(4)));

#ifndef __has_builtin
#define __has_builtin(x) 0
#endif

__device__ __forceinline__ unsigned short f2bf(float f) {
    unsigned int u = __float_as_uint(f);
    u = (u + 0x7fffu + ((u >> 16) & 1u)) >> 16;  // RNE
    return (unsigned short)u;
}
__device__ __forceinline__ unsigned int pack2(float a, float b) {
    return (unsigned int)f2bf(a) | ((unsigned int)f2bf(b) << 16);
}
// fast pack (round-half-up): 2 adds + 1 v_perm
__device__ __forceinline__ unsigned int pack2_fast(float a, float b) {
#if __has_builtin(__builtin_amdgcn_perm)
    return __builtin_amdgcn_perm(__float_as_uint(b) + 0x8000u,
                                 __float_as_uint(a) + 0x8000u, 0x07060302u);
#else
    return ((__float_as_uint(a) + 0x8000u) >> 16) |
           ((__float_as_uint(b) + 0x8000u) & 0xffff0000u);
#endif
}

// async global->LDS, 16B per lane; LDS dest = wave-uniform base + lane*16
__device__ __forceinline__ void gload_lds16(const unsigned short* g, unsigned short* l) {
    __builtin_amdgcn_global_load_lds(
        (const __attribute__((address_space(1))) void*)g,
        (__attribute__((address_space(3))) void*)l, 16, 0, 0);
}

// ---------------- fused prep: cast x -> bf16, transpose W -> bf16 [n][k] ----------------
// blocks [0,2048): cast_x (8 elems/thread).  blocks [2048,6144): W transpose.
__global__ __launch_bounds__(256) void prep_kernel(const float* __restrict__ x,
                                                   const float* __restrict__ Wq,
                                                   const float* __restrict__ Wk,
                                                   const float* __restrict__ Wv,
                                                   const float* __restrict__ Wo,
                                                   unsigned short* __restrict__ Xb,
                                                   unsigned short* __restrict__ Wqkvt,
                                                   unsigned short* __restrict__ Wot) {
    __shared__ float tile[32][33];
    const int bx = blockIdx.x;
    const int t = threadIdx.x;
    if (bx < 2048) {
        int gid = bx * 256 + t;
        int i = gid * 8;
        float4 a = *(const float4*)(x + i);
        float4 b = *(const float4*)(x + i + 4);
        uint4 o;
        o.x = pack2(a.x, a.y); o.y = pack2(a.z, a.w);
        o.z = pack2(b.x, b.y); o.w = pack2(b.z, b.w);
        ((uint4*)Xb)[gid] = o;
        return;
    }
    int pb = bx - 2048;
    int p = pb >> 10, rem = pb & 1023;
    int bxx = rem & 31, byy = rem >> 5;
    const float* src = (p == 0) ? Wq : (p == 1) ? Wk : (p == 2) ? Wv : Wo;
    unsigned short* dst = (p == 3) ? Wot : (Wqkvt + (size_t)p * DD * DD);
    int tx = t & 31, ty = t >> 5;
    int n = bxx * 32 + tx;
#pragma unroll
    for (int i = 0; i < 4; ++i) {
        int k = byy * 32 + ty + i * 8;
        tile[ty + i * 8][tx] = src[k * DD + n];
    }
    __syncthreads();
#pragma unroll
    for (int i = 0; i < 4; ++i) {
        int n2 = bxx * 32 + ty + i * 8;
        int k2 = byy * 32 + tx;
        dst[n2 * DD + k2] = f2bf(tile[tx][ty + i * 8]);
    }
}

// ============ 128x128-tile GEMM K-loop, global_load_lds staging, xor-swizzled ============
// Phys granule p (16B) of LDS row r holds logical granule p^(r&7): DMA writes stay
// contiguous (conflict-free), fragment b128 reads spread over all 8 granule groups
// (2 accesses/bank/quarter = structural minimum, zero conflicts). Rows are 128B = full
// bank line — do NOT shorten rows (64B rows -> 4-way conflicts, r3 lesson).
#define GEMM_K_LOOP(Aglob, Bglob)                                                 \
    __shared__ unsigned short smem[128 * 132];                                    \
    unsigned short (*As)[64]  = (unsigned short(*)[64])smem;                      \
    unsigned short (*Bs)[64]  = (unsigned short(*)[64])(smem + 128 * 64);         \
    unsigned short (*Es)[132] = (unsigned short(*)[132])smem;                     \
    const int n0 = blockIdx.x * 128, m0 = blockIdx.y * 128;                       \
    const int t = threadIdx.x;                                                    \
    const int wave = t >> 6, lane = t & 63;                                       \
    const int wm = wave >> 1, wn = wave & 1;                                      \
    const int l15 = lane & 15, quad = lane >> 4;                                  \
    const int lr = lane >> 3, lg = (lane & 7);                                    \
    const int lc = (lg ^ lr) * 8;   /* swizzled source granule */                 \
    f32x4 acc[4][4];                                                              \
    _Pragma("unroll") for (int i = 0; i < 4; ++i)                                 \
        _Pragma("unroll") for (int j = 0; j < 4; ++j) acc[i][j] = f32x4{0,0,0,0}; \
    for (int kt = 0; kt < 16; ++kt) {                                             \
        if (kt) __syncthreads();                                                  \
        _Pragma("unroll") for (int i = 0; i < 4; ++i) {                           \
            int row = wave * 32 + i * 8;                                          \
            gload_lds16(Aglob + (size_t)(m0 + row + lr) * DD + kt * 64 + lc, &As[row][0]); \
            gload_lds16(Bglob + (size_t)(n0 + row + lr) * DD + kt * 64 + lc, &Bs[row][0]); \
        }                                                                         \
        __syncthreads();                                                          \
        _Pragma("unroll") for (int kh = 0; kh < 2; ++kh) {                        \
            bf16x8 af[4], bfr[4];                                                 \
            _Pragma("unroll") for (int s = 0; s < 4; ++s)                         \
                af[s] = *(const bf16x8*)&As[wm * 64 + s * 16 + l15][((kh * 4 + quad) ^ (l15 & 7)) * 8]; \
            _Pragma("unroll") for (int s = 0; s < 4; ++s)                         \
                bfr[s] = *(const bf16x8*)&Bs[wn * 64 + s * 16 + l15][((kh * 4 + quad) ^ (l15 & 7)) * 8]; \
            _Pragma("unroll") for (int i = 0; i < 4; ++i)                         \
                _Pragma("unroll") for (int j = 0; j < 4; ++j)                     \
                    acc[i][j] = __builtin_amdgcn_mfma_f32_16x16x32_bf16(af[i], bfr[j], acc[i][j], 0, 0, 0); \
        }                                                                         \
    }                                                                             \
    __syncthreads();   /* K-loop done; smem reusable */

// ---------------- QKV fused GEMM; LDS-transpose epilogue; Q pre-scaled ----------------
// (round-0 structure: measured ~28 us = ~920 TF, at the 2-barrier-structure ceiling)
// V is stored to global in the attention LDS *physical* layout: within each 128-key
// tile of row hd, physical 8B slot p holds logical slot p ^ (hd&15).  This makes the
// attn V b64 reads bank-conflict-free at quarter-wave granularity (r5 profile: 4.2M
// conflict cycles were all on the V path; 16B-granule swizzle can't fix it because
// quad&1 is constant within a quarter-wave).
__global__ __launch_bounds__(256) void qkv_gemm_kernel(const unsigned short* __restrict__ Xb,
                                                       const unsigned short* __restrict__ Wt,
                                                       unsigned short* __restrict__ Qg,
                                                       unsigned short* __restrict__ Kg,
                                                       unsigned short* __restrict__ Vt) {
    GEMM_K_LOOP(Xb, Wt)
    const int p = n0 >> 10;   // projection uniform per block
    const float qs = (p == 0) ? 0.18033688011112042f : 1.0f;  // log2(e)/sqrt(HD) folded into Q
    if (p < 2) {
#pragma unroll
        for (int sm = 0; sm < 4; ++sm)
#pragma unroll
            for (int sn = 0; sn < 4; ++sn)
#pragma unroll
                for (int i = 0; i < 4; ++i)
                    Es[wm * 64 + sm * 16 + quad * 4 + i][wn * 64 + sn * 16 + l15] = f2bf(acc[sm][sn][i] * qs);
    } else {
#pragma unroll
        for (int sm = 0; sm < 4; ++sm)
#pragma unroll
            for (int sn = 0; sn < 4; ++sn)
#pragma unroll
                for (int i = 0; i < 4; ++i)
                    Es[wn * 64 + sn * 16 + l15][wm * 64 + sm * 16 + quad * 4 + i] = f2bf(acc[sm][sn][i]);
    }
    __syncthreads();
    const int h0 = (n0 & 1023) >> 6;
    if (p < 2) {
        unsigned short* dst0 = p ? Kg : Qg;
        int ml = t >> 1, seg = t & 1;
        int gm = m0 + ml, b = gm >> 11, s = gm & 2047;
        unsigned short* dptr = dst0 + ((size_t)(b * HH + h0 + seg) * SS + s) * HD;
#pragma unroll
        for (int j = 0; j < 8; ++j)
            *(uint4*)(dptr + j * 8) = *(const uint4*)&Es[ml][seg * 64 + j * 8];
    } else {
        int nl = t >> 1, mh = t & 1;
        int h = h0 + (nl >> 6), hd = nl & 63;
        int b = m0 >> 11;
        const int o = hd & 15, e = o & ~1, sw = o & 1;
        // row base; keys are placed at swizzled slots within the 128-key tile (m0-aligned)
        unsigned short* rowp = Vt + ((size_t)(b * HH + h) * HD + hd) * SS + (m0 & 2047);
#pragma unroll
        for (int j = 0; j < 8; ++j) {
            uint4 v = *(const uint4*)&Es[nl][mh * 64 + j * 8];
            if (sw) { unsigned t0 = v.x, t1 = v.y; v.x = v.z; v.y = v.w; v.z = t0; v.w = t1; }
            int Q = (mh * 16 + 2 * j) ^ e;   // physical 8B-slot pair base (even)
            *(uint4*)(rowp + Q * 4) = v;
        }
    }
}

// ---------------- Output projection: out = Ctx @ Wo + bo (fp32 out) ----------------
__global__ __launch_bounds__(256) void out_gemm_kernel(const unsigned short* __restrict__ Ctxb,
                                                       const unsigned short* __restrict__ Wot,
                                                       const float* __restrict__ bo,
                                                       float* __restrict__ out) {
    GEMM_K_LOOP(Ctxb, Wot)
    (void)Es;
#pragma unroll
    for (int sn = 0; sn < 4; ++sn) {
        int gn = n0 + wn * 64 + sn * 16 + l15;
        float bias = bo[gn];
#pragma unroll
        for (int sm = 0; sm < 4; ++sm)
#pragma unroll
            for (int i = 0; i < 4; ++i) {
                int gm = m0 + wm * 64 + sm * 16 + quad * 4 + i;
                out[(size_t)gm * DD + gn] = acc[sm][sn][i] + bias;
            }
    }
}

// ---------------- MFMA flash attention (round-0 structure) ----------------
// 64-q blocks x 128-key double-buffered tiles, grid 1024 (2 dispatch rounds, big-first
// = dynamic load balance). No setprio (r4/r5 A/B: null on this lockstep structure).
// V LDS layout = global Vt layout (pre-swizzled at 8B slots by qkv epilogue):
// phys slot p of row r holds logical slot p^(r&15) -> V b64 reads hit all 32 banks
// per quarter-wave (conflict-free); DMA is a plain linear copy.
__global__ __launch_bounds__(256) void attn_kernel(const unsigned short* __restrict__ Qg,
                                                   const unsigned short* __restrict__ Kg,
                                                   const unsigned short* __restrict__ Vt,
                                                   unsigned short* __restrict__ Ctxb) {
    __shared__ unsigned short Ks[2][128][64];
    __shared__ unsigned short Vs[2][64][128];

    const int bh = blockIdx.x;
    const int qt = (int)gridDim.y - 1 - (int)blockIdx.y;   // big tiles first
    const int t = threadIdx.x;
    const int wave = t >> 6, lane = t & 63;
    const int l15 = lane & 15, quad = lane >> 4;
    const int q0 = qt * 64;
    const int qmax = q0 + 63;
    const int b = bh >> 4, h = bh & 15;

    const unsigned short* Qb = Qg + (size_t)bh * SS * HD;
    const unsigned short* Kb = Kg + (size_t)bh * SS * HD;
    const unsigned short* Vb = Vt + (size_t)bh * HD * SS;

    // Q fragment (B operand): B[n=q=l15][k=hd=hh*32+quad*8+j]; Q pre-scaled
    const int qrow = q0 + wave * 16 + l15;
    bf16x8 bq[2];
#pragma unroll
    for (int hh = 0; hh < 2; ++hh)
        bq[hh] = *(const bf16x8*)(Qb + (size_t)qrow * HD + hh * 32 + quad * 8);

    // DMA lane decomposition; K source is granule-swizzled, V source is already
    // physically laid out (linear copy).
    const int rloc = lane >> 3, pcl = lane & 7;   // K: 8 rows x 8 granules (16B)
    const int vrl = lane >> 4, vgc = lane & 15;   // V: 4 rows x 16 granules (16B)
    const unsigned short* ksrc[4];
    const unsigned short* vsrc[4];
#pragma unroll
    for (int j = 0; j < 4; ++j) {
        int krow = (wave * 4 + j) * 8 + rloc;
        ksrc[j] = Kb + (size_t)krow * HD + (pcl ^ rloc) * 8;
        int vrow = wave * 16 + j * 4 + vrl;
        vsrc[j] = Vb + (size_t)vrow * SS + vgc * 8;
    }

    f32x4 acc[4] = {f32x4{0,0,0,0}, f32x4{0,0,0,0}, f32x4{0,0,0,0}, f32x4{0,0,0,0}};
    float l = 0.f;   // lane-local partial; cross-quad reduce once at end
    const int nkt = (qmax >> 7) + 1;

    // prologue: tile 0 -> buf 0
#pragma unroll
    for (int j = 0; j < 4; ++j) {
        gload_lds16(ksrc[j], &Ks[0][(wave * 4 + j) * 8][0]);
        gload_lds16(vsrc[j], &Vs[0][wave * 16 + j * 4][0]);
    }
    __syncthreads();

    for (int kt = 0; kt < nkt; ++kt) {
        const int buf = kt & 1;
        const int k0 = kt * 128;
        if (kt + 1 < nkt) {
            const int nb = buf ^ 1;
#pragma unroll
            for (int j = 0; j < 4; ++j) {
                gload_lds16(ksrc[j] + (size_t)(kt + 1) * 128 * HD, &Ks[nb][(wave * 4 + j) * 8][0]);
                gload_lds16(vsrc[j] + (kt + 1) * 128,              &Vs[nb][wave * 16 + j * 4][0]);
            }
        }

        auto tile_body = [&](int kbmax, bool tail) {
#pragma unroll
            for (int kb = 0; kb < 8; ++kb) {
                if (kb >= kbmax) continue;   // wave-uniform branch
                // QK: S^T = K.Q^T  D[m=key][n=q]
                f32x4 St = f32x4{0, 0, 0, 0};
#pragma unroll
                for (int hh = 0; hh < 2; ++hh) {
                    bf16x8 ak = *(const bf16x8*)&Ks[buf][kb * 16 + l15][((hh * 4 + quad) ^ (l15 & 7)) * 8];
                    St = __builtin_amdgcn_mfma_f32_16x16x32_bf16(ak, bq[hh], St, 0, 0, 0);
                }
                if (tail) {
#pragma unroll
                    for (int r = 0; r < 4; ++r)
                        if (k0 + kb * 16 + quad * 4 + r > qrow) St[r] = -1e30f;
                }
                float e0 = __builtin_amdgcn_exp2f(St[0]);
                float e1 = __builtin_amdgcn_exp2f(St[1]);
                float e2 = __builtin_amdgcn_exp2f(St[2]);
                float e3 = __builtin_amdgcn_exp2f(St[3]);
                l += (e0 + e1) + (e2 + e3);
                uint2 uu;
                uu.x = pack2_fast(e0, e1);
                uu.y = pack2_fast(e2, e3);
                s16x4 ap = *(s16x4*)&uu;
                // PV: ctx += P @ V  (8B-slot swizzled V^T reads, conflict-free)
#pragma unroll
                for (int db = 0; db < 4; ++db) {
                    s16x4 bv = *(const s16x4*)&Vs[buf][db * 16 + l15][((4 * kb + quad) ^ l15) * 4];
                    acc[db] = __builtin_amdgcn_mfma_f32_16x16x16bf16_1k(ap, bv, acc[db], 0, 0, 0);
                }
            }
        };
        if (kt == nkt - 1) tile_body(((q0 - k0) >> 4) + wave + 1, true);  // per-wave diagonal bound
        else               tile_body(8, false);

        if (kt + 1 < nkt) __syncthreads();   // last tile: no LDS writer follows
    }

    // epilogue: reduce l across quads, ctx/l -> bf16 [B*S][D]
    l += __shfl_xor(l, 16, 64);
    l += __shfl_xor(l, 32, 64);
    float linv = 1.0f / l;
#pragma unroll
    for (int r = 0; r < 4; ++r) {
        float ir = __shfl(linv, quad * 4 + r, 64);
        int gq = q0 + wave * 16 + quad * 4 + r;
        size_t base = ((size_t)(b * SS + gq)) * DD + h * HD;
#pragma unroll
        for (int db = 0; db < 4; ++db)
            Ctxb[base + db * 16 + l15] = f2bf(acc[db][r] * ir);
    }
}

// ---------------- launcher ----------------
// Workspace (<= 48 MiB):
//   [0,8M)    Xb     bf16 [4096][1024]
//   [8M,14M)  Wqkvt  bf16 [3][1024][1024]   (W^T [n][k])
//   [14M,16M) Wot    bf16 [1024][1024]      (W^T)
//   [16M,24M) Qg     bf16 [32][2048][64]    (pre-scaled by log2e/8)
//   [24M,32M) Kg     bf16 [32][2048][64]
//   [32M,40M) Vt     bf16 [32][64][2048]    (transposed, 8B-slot swizzled per 128-key tile)
//   [40M,48M) Ctxb   bf16 [4096][1024]
extern "C" void kernel_launch(void* const* d_in, const int* in_sizes, int n_in,
                              void* d_out, int out_size, void* d_ws, size_t ws_size,
                              hipStream_t stream) {
    const float* x  = (const float*)d_in[0];
    const float* Wq = (const float*)d_in[1];
    const float* Wk = (const float*)d_in[2];
    const float* Wv = (const float*)d_in[3];
    const float* Wo = (const float*)d_in[4];
    const float* bo = (const float*)d_in[5];
    float* out = (float*)d_out;

    char* w = (char*)d_ws;
    unsigned short* Xb    = (unsigned short*)(w);
    unsigned short* Wqkvt = (unsigned short*)(w + (size_t)(8 << 20));
    unsigned short* Wot   = (unsigned short*)(w + (size_t)(14 << 20));
    unsigned short* Qg    = (unsigned short*)(w + (size_t)(16 << 20));
    unsigned short* Kg    = (unsigned short*)(w + (size_t)(24 << 20));
    unsigned short* Vt    = (unsigned short*)(w + (size_t)(32 << 20));
    unsigned short* Ctxb  = (unsigned short*)(w + (size_t)(40 << 20));

    prep_kernel<<<6144, 256, 0, stream>>>(x, Wq, Wk, Wv, Wo, Xb, Wqkvt, Wot);
    qkv_gemm_kernel<<<dim3(3 * DD / 128, MM / 128), 256, 0, stream>>>(Xb, Wqkvt, Qg, Kg, Vt);
    attn_kernel<<<dim3(BB * HH, SS / 64), 256, 0, stream>>>(Qg, Kg, Vt, Ctxb);
    out_gemm_kernel<<<dim3(DD / 128, MM / 128), 256, 0, stream>>>(Ctxb, Wot, bo, out);
}